// Round 4
// baseline (1934.006 us; speedup 1.0000x reference)
//
#include <hip/hip_runtime.h>

#define NN 50000
#define DD 64
#define EE 800000
#define NBKT 3125              // 200000 / 64 nodes per bucket
#define BN_EPS 1e-5f
#define NEG 0.01f

typedef float4 f4;

__device__ __forceinline__ float b2f(unsigned short u) {
    return __uint_as_float(((unsigned)u) << 16);
}
__device__ __forceinline__ unsigned short f2b(float x) {
    unsigned u = __float_as_uint(x);
    u += 0x7fffu + ((u >> 16) & 1u);   // RNE
    return (unsigned short)(u >> 16);
}

// ---- precompute rel vectors for all steps 0..3, write final rels to output ----
__global__ __launch_bounds__(256) void k_rels(
    const float* __restrict__ nr, const float* __restrict__ poir,
    const float* __restrict__ sr, const float* __restrict__ dr,
    const float* __restrict__ relW, const float* __restrict__ relb,
    float* __restrict__ rels_all, float* __restrict__ rel_out) {
    __shared__ float cur[4][64];
    int tid = threadIdx.x;
    int k = tid >> 6, j = tid & 63;
    const float* r0 = (k == 0) ? nr : (k == 1) ? poir : (k == 2) ? sr : dr;
    float v = r0[j];
    cur[k][j] = v;
    rels_all[(0 * 4 + k) * 64 + j] = v;
    __syncthreads();
    for (int s = 0; s < 3; ++s) {
        const float* W = relW + s * 4096;
        float acc = relb[s * 64 + j];
        #pragma unroll 8
        for (int kk = 0; kk < 64; ++kk) acc += cur[k][kk] * W[j * 64 + kk];
        __syncthreads();
        cur[k][j] = acc;
        rels_all[((s + 1) * 4 + k) * 64 + j] = acc;
        __syncthreads();
    }
    rel_out[k * 64 + j] = cur[k][j];
}

// ---- bucket histogram: bcnt[flat_dst >> 6]++ ----
__global__ __launch_bounds__(256) void k_bhist(
    const int* __restrict__ e0, const int* __restrict__ e1,
    const int* __restrict__ e2, const int* __restrict__ e3,
    int* __restrict__ bcnt) {
    int idx = blockIdx.x * 256 + threadIdx.x;        // over 4*EE exact
    int k = idx / EE;
    int e = idx - k * EE;
    const int* ed = (k == 0) ? e0 : (k == 1) ? e1 : (k == 2) ? e2 : e3;
    int dst = ed[EE + e];
    atomicAdd(&bcnt[(k * NN + dst) >> 6], 1);
}

// ---- scan bucket counts -> boff (exclusive); zero bucket cursors ----
__global__ __launch_bounds__(256) void k_bscan(const int* __restrict__ bcnt,
                                               int* __restrict__ boff,
                                               int* __restrict__ bcur) {
    __shared__ int s[256];
    __shared__ int carry;
    int tid = threadIdx.x;
    if (tid == 0) carry = 0;
    __syncthreads();
    for (int base = 0; base < NBKT; base += 256) {
        int i = base + tid;
        int v = (i < NBKT) ? bcnt[i] : 0;
        s[tid] = v;
        __syncthreads();
        for (int d = 1; d < 256; d <<= 1) {
            int t = (tid >= d) ? s[tid - d] : 0;
            __syncthreads();
            s[tid] += t;
            __syncthreads();
        }
        int c = carry;
        if (i < NBKT) { boff[i] = s[tid] - v + c; bcur[i] = 0; }
        __syncthreads();
        if (tid == 0) carry = c + s[255];
        __syncthreads();
    }
    if (tid == 0) boff[NBKT] = carry;   // = 4*EE
}

// ---- scatter edges into bucket-contiguous staging {flat_src, flat_dst} ----
__global__ __launch_bounds__(256) void k_bscat(
    const int* __restrict__ e0, const int* __restrict__ e1,
    const int* __restrict__ e2, const int* __restrict__ e3,
    const int* __restrict__ boff, int* __restrict__ bcur,
    int2* __restrict__ stage) {
    int idx = blockIdx.x * 256 + threadIdx.x;
    int k = idx / EE;
    int e = idx - k * EE;
    const int* ed = (k == 0) ? e0 : (k == 1) ? e1 : (k == 2) ? e2 : e3;
    int src = ed[e], dst = ed[EE + e];
    int v = k * NN + dst;
    int b = v >> 6;
    int p = atomicAdd(&bcur[b], 1);
    stage[boff[b] + p] = make_int2(k * NN + src, v);
}

// ---- per-bucket finish: LDS histogram+scan, write off/dinv, place csr ----
__global__ __launch_bounds__(256) void k_fine(
    const int2* __restrict__ stage, const int* __restrict__ boff,
    int* __restrict__ off, float* __restrict__ dinv, int* __restrict__ csr) {
    __shared__ int cnt[64], noff[64], curl[64];
    int tid = threadIdx.x;
    int b = blockIdx.x;
    if (tid < 64) cnt[tid] = 0;
    __syncthreads();
    int e0 = boff[b], e1 = boff[b + 1];
    for (int i = e0 + tid; i < e1; i += 256)
        atomicAdd(&cnt[stage[i].y & 63], 1);
    __syncthreads();
    if (tid < 64) {
        int c0 = cnt[tid];
        int c = c0;
        #pragma unroll
        for (int d = 1; d < 64; d <<= 1) {
            int t = __shfl_up(c, d, 64);
            if (tid >= d) c += t;
        }
        int ex = e0 + c - c0;          // exclusive offset
        noff[tid] = ex;
        curl[tid] = 0;
        off[b * 64 + tid] = ex;
        dinv[b * 64 + tid] = rsqrtf((float)(c0 + 1));
    }
    __syncthreads();
    for (int i = e0 + tid; i < e1; i += 256) {
        int2 en = stage[i];
        int j = en.y & 63;
        int p = atomicAdd(&curl[j], 1);
        csr[noff[j] + p] = en.x;
    }
    if (b == 0 && tid == 0) off[4 * NN] = 4 * EE;
}

// ---- fused GEMM: [optional BN+leaky+residual] then h_bf = (e .* rel) @ W ----
// mode 0: prev=feat, no BN.  mode 1: prev=feat, BN(agg), write e1.
// mode 2: prev=e1, BN(agg), no write.
__global__ __launch_bounds__(256) void k_gemm(
    const float* __restrict__ prevbuf, size_t prev_ka_stride,
    const float* __restrict__ agg, const float* __restrict__ stats,
    const float* __restrict__ gamma, const float* __restrict__ beta,
    const float* __restrict__ rels, const float* __restrict__ W,
    float* __restrict__ e1, unsigned short* __restrict__ h_bf, int mode) {
    __shared__ float Wl[4096];
    __shared__ float xl[16][68];
    int tid = threadIdx.x;
    int ka = blockIdx.y;
    int row0 = blockIdx.x * 16;
    {
        const f4* W4 = (const f4*)W;
        f4* Wl4 = (f4*)Wl;
        Wl4[tid] = W4[tid];
        Wl4[tid + 256] = W4[tid + 256];
        Wl4[tid + 512] = W4[tid + 512];
        Wl4[tid + 768] = W4[tid + 768];
    }
    int rl = tid >> 4, c4 = (tid & 15) * 4;
    int row = row0 + rl;
    size_t kabase = (size_t)ka * NN * DD;
    {
        f4 pv = *(const f4*)(prevbuf + (size_t)ka * prev_ka_stride + (size_t)row * DD + c4);
        if (mode > 0) {
            f4 av = *(const f4*)(agg + kabase + (size_t)row * DD + c4);
            float* a = &av.x;
            float* p = &pv.x;
            #pragma unroll
            for (int j = 0; j < 4; ++j) {
                int col = c4 + j;
                float mean = stats[ka * 128 + col] * (1.0f / NN);
                float m2 = stats[ka * 128 + 64 + col] * (1.0f / NN);
                float inv = rsqrtf(m2 - mean * mean + BN_EPS);
                float xn = gamma[col] * (a[j] - mean) * inv + beta[col];
                p[j] += (xn >= 0.f) ? xn : NEG * xn;
            }
            if (mode == 1) *(f4*)(e1 + kabase + (size_t)row * DD + c4) = pv;
        }
        f4 rv = *(const f4*)(rels + ka * 64 + c4);
        xl[rl][c4 + 0] = pv.x * rv.x;
        xl[rl][c4 + 1] = pv.y * rv.y;
        xl[rl][c4 + 2] = pv.z * rv.z;
        xl[rl][c4 + 3] = pv.w * rv.w;
    }
    __syncthreads();
    float ax = 0.f, ay = 0.f, az = 0.f, aw = 0.f;
    #pragma unroll
    for (int kk = 0; kk < 64; ++kk) {
        float xv = xl[rl][kk];
        const float* wrow = Wl + kk * 64 + c4;
        ax += xv * wrow[0];
        ay += xv * wrow[1];
        az += xv * wrow[2];
        aw += xv * wrow[3];
    }
    ushort4 o;
    o.x = f2b(ax); o.y = f2b(ay); o.z = f2b(az); o.w = f2b(aw);
    *(ushort4*)(h_bf + kabase + (size_t)row * DD + c4) = o;
}

// ---- gather: wave = 1 dst node; lane = (edge-group g, feature-quad fq) ----
// acc = b + selfloop + sum_in h_bf[src]*norm ; optional fused BN stats
template <int STATS>
__global__ __launch_bounds__(256) void k_gather(
    const unsigned short* __restrict__ h_bf, const int* __restrict__ csr,
    const int* __restrict__ off, const float* __restrict__ dinv,
    const float* __restrict__ bias, float* __restrict__ dstbuf,
    float* __restrict__ stats_c) {
    __shared__ float sst[128];
    int tid = threadIdx.x;
    if (STATS && tid < 128) sst[tid] = 0.f;
    if (STATS) __syncthreads();
    int lane = tid & 63, w = tid >> 6;
    int v = blockIdx.x * 4 + w;               // flat node id (relation-major)
    int g = lane >> 4, fq = lane & 15;
    int s0 = off[v], s1 = off[v + 1];
    float di = dinv[v];
    float ax = 0.f, ay = 0.f, az = 0.f, aw = 0.f;
    #pragma unroll 2
    for (int i = s0; i < s1; i += 4) {
        int e = i + g;
        if (e < s1) {
            int sf = csr[e];
            float nm = dinv[sf] * di;
            ushort4 hv = *(const ushort4*)(h_bf + (size_t)sf * DD + fq * 4);
            ax += b2f(hv.x) * nm;
            ay += b2f(hv.y) * nm;
            az += b2f(hv.z) * nm;
            aw += b2f(hv.w) * nm;
        }
    }
    ax += __shfl_xor(ax, 16); ay += __shfl_xor(ay, 16);
    az += __shfl_xor(az, 16); aw += __shfl_xor(aw, 16);
    ax += __shfl_xor(ax, 32); ay += __shfl_xor(ay, 32);
    az += __shfl_xor(az, 32); aw += __shfl_xor(aw, 32);
    if (lane < 16) {
        ushort4 hd = *(const ushort4*)(h_bf + (size_t)v * DD + fq * 4);
        float d2 = di * di;
        f4 bv = *(const f4*)(bias + fq * 4);
        f4 o;
        o.x = bv.x + b2f(hd.x) * d2 + ax;
        o.y = bv.y + b2f(hd.y) * d2 + ay;
        o.z = bv.z + b2f(hd.z) * d2 + az;
        o.w = bv.w + b2f(hd.w) * d2 + aw;
        *(f4*)(dstbuf + (size_t)v * DD + fq * 4) = o;
        if (STATS) {
            atomicAdd(&sst[fq * 4 + 0], o.x);
            atomicAdd(&sst[fq * 4 + 1], o.y);
            atomicAdd(&sst[fq * 4 + 2], o.z);
            atomicAdd(&sst[fq * 4 + 3], o.w);
            atomicAdd(&sst[64 + fq * 4 + 0], o.x * o.x);
            atomicAdd(&sst[64 + fq * 4 + 1], o.y * o.y);
            atomicAdd(&sst[64 + fq * 4 + 2], o.z * o.z);
            atomicAdd(&sst[64 + fq * 4 + 3], o.w * o.w);
        }
    }
    if (STATS) {
        __syncthreads();
        if (tid < 128) {
            int ka = blockIdx.x / (NN / 4);
            atomicAdd(stats_c + (size_t)(blockIdx.x & 63) * 512 + ka * 128 + tid,
                      sst[tid]);
        }
    }
}

// ---- reduce 64 stats copies -> stats[512] ----
__global__ __launch_bounds__(256) void k_sreduce(const float* __restrict__ stats_c,
                                                 float* __restrict__ stats) {
    int j = blockIdx.x * 256 + threadIdx.x;   // 512 total
    float s = 0.f;
    #pragma unroll 8
    for (int c = 0; c < 64; ++c) s += stats_c[(size_t)c * 512 + j];
    stats[j] = s;
}

extern "C" void kernel_launch(void* const* d_in, const int* in_sizes, int n_in,
                              void* d_out, int out_size, void* d_ws, size_t ws_size,
                              hipStream_t stream) {
    const float* feat = (const float*)d_in[0];
    const float* poir = (const float*)d_in[1];
    const float* sr   = (const float*)d_in[2];
    const float* dr   = (const float*)d_in[3];
    const float* nr   = (const float*)d_in[4];
    const int* e_poi  = (const int*)d_in[5];
    const int* e_s    = (const int*)d_in[6];
    const int* e_d    = (const int*)d_in[7];
    const int* e_n    = (const int*)d_in[8];
    const float* gcnW = (const float*)d_in[9];
    const float* gcnb = (const float*)d_in[10];
    const float* bng  = (const float*)d_in[11];
    const float* bnb  = (const float*)d_in[12];
    const float* relW = (const float*)d_in[13];
    const float* relb = (const float*)d_in[14];

    float* out = (float*)d_out;
    float* rel_out = out + (size_t)4 * NN * DD;
    float* ws = (float*)d_ws;

    // workspace layout (4-byte words, regions 16B-aligned)
    size_t o = 0;
    auto alloc = [&](size_t words) { o = (o + 3) & ~(size_t)3; size_t r = o; o += words; return r; };
    float* dinv     = ws + alloc(200000);
    float* rels_all = ws + alloc(1024);
    float* stats    = ws + alloc(512);
    float* stats_c  = ws + alloc(64 * 512);
    int*   bcnt     = (int*)(ws + alloc(NBKT));
    int*   boff     = (int*)(ws + alloc(NBKT + 1));
    int*   bcur     = (int*)(ws + alloc(NBKT));
    int*   off      = (int*)(ws + alloc(4 * NN + 1));
    int2*  stage    = (int2*)(ws + alloc((size_t)8 * EE));      // 4*EE int2
    int*   csr      = (int*)(ws + alloc((size_t)4 * EE));
    unsigned short* h_bf = (unsigned short*)(ws + alloc((size_t)2 * NN * DD)); // 4*NN*DD ushort
    float* agg      = ws + alloc((size_t)4 * NN * DD);
    float* e1       = ws + alloc((size_t)4 * NN * DD);

    const int* E0 = e_n;  const int* E1 = e_poi;
    const int* E2 = e_s;  const int* E3 = e_d;

    k_rels<<<1, 256, 0, stream>>>(nr, poir, sr, dr, relW, relb, rels_all, rel_out);
    hipMemsetAsync(bcnt, 0, NBKT * sizeof(int), stream);
    k_bhist<<<(4 * EE) / 256, 256, 0, stream>>>(E0, E1, E2, E3, bcnt);
    k_bscan<<<1, 256, 0, stream>>>(bcnt, boff, bcur);
    k_bscat<<<(4 * EE) / 256, 256, 0, stream>>>(E0, E1, E2, E3, boff, bcur, stage);
    k_fine<<<NBKT, 256, 0, stream>>>(stage, boff, off, dinv, csr);

    for (int l = 0; l < 3; ++l) {
        const float* Wl = gcnW + l * 4096;
        const float* bl = gcnb + l * 64;
        const float* rl = rels_all + l * 256;
        if (l == 0) {
            k_gemm<<<dim3(3125, 4), 256, 0, stream>>>(
                feat, (size_t)0, nullptr, nullptr, nullptr, nullptr,
                rl, Wl, nullptr, h_bf, 0);
        } else if (l == 1) {
            k_gemm<<<dim3(3125, 4), 256, 0, stream>>>(
                feat, (size_t)0, agg, stats, bng + 0 * 64, bnb + 0 * 64,
                rl, Wl, e1, h_bf, 1);
        } else {
            k_gemm<<<dim3(3125, 4), 256, 0, stream>>>(
                e1, (size_t)(NN * DD), agg, stats, bng + 1 * 64, bnb + 1 * 64,
                rl, Wl, nullptr, h_bf, 2);
        }
        if (l < 2) {
            hipMemsetAsync(stats_c, 0, 64 * 512 * sizeof(float), stream);
            k_gather<1><<<NN, 256, 0, stream>>>(h_bf, csr, off, dinv, bl, agg, stats_c);
            k_sreduce<<<2, 256, 0, stream>>>(stats_c, stats);
        } else {
            k_gather<0><<<NN, 256, 0, stream>>>(h_bf, csr, off, dinv, bl, out, nullptr);
        }
    }
}

// Round 6
// 903.993 us; speedup vs baseline: 2.1394x; 2.1394x over previous
//
#include <hip/hip_runtime.h>

#define NN 50000
#define DD 64
#define EE 800000
#define BN_EPS 1e-5f
#define NEG 0.01f

typedef float4 f4;

__device__ __forceinline__ float b2f(unsigned short u) {
    return __uint_as_float(((unsigned)u) << 16);
}
__device__ __forceinline__ unsigned short f2b(float x) {
    unsigned u = __float_as_uint(x);
    u += 0x7fffu + ((u >> 16) & 1u);   // RNE
    return (unsigned short)(u >> 16);
}

// ---- rel vectors for steps 0..3 + zero BN stats (fused housekeeping) ----
__global__ __launch_bounds__(256) void k_rels(
    const float* __restrict__ nr, const float* __restrict__ poir,
    const float* __restrict__ sr, const float* __restrict__ dr,
    const float* __restrict__ relW, const float* __restrict__ relb,
    float* __restrict__ rels_all, float* __restrict__ rel_out,
    float* __restrict__ stats) {
    __shared__ float cur[4][64];
    int tid = threadIdx.x;
    stats[tid] = 0.f; stats[tid + 256] = 0.f;
    stats[tid + 512] = 0.f; stats[tid + 768] = 0.f;
    int k = tid >> 6, j = tid & 63;
    const float* r0 = (k == 0) ? nr : (k == 1) ? poir : (k == 2) ? sr : dr;
    float v = r0[j];
    cur[k][j] = v;
    rels_all[(0 * 4 + k) * 64 + j] = v;
    __syncthreads();
    for (int s = 0; s < 3; ++s) {
        const float* W = relW + s * 4096;
        float acc = relb[s * 64 + j];
        #pragma unroll 8
        for (int kk = 0; kk < 64; ++kk) acc += cur[k][kk] * W[j * 64 + kk];
        __syncthreads();
        cur[k][j] = acc;
        rels_all[((s + 1) * 4 + k) * 64 + j] = acc;
        __syncthreads();
    }
    rel_out[k * 64 + j] = cur[k][j];
}

// ---- int degree count (low-contention: 200k counters) ----
__global__ __launch_bounds__(256) void k_deg_count(
    const int* __restrict__ e0, const int* __restrict__ e1,
    const int* __restrict__ e2, const int* __restrict__ e3,
    int* __restrict__ ideg) {
    int idx = blockIdx.x * 256 + threadIdx.x;
    int k = idx / EE;
    int e = idx - k * EE;
    const int* ed = (k == 0) ? e0 : (k == 1) ? e1 : (k == 2) ? e2 : e3;
    int dst = ed[EE + e];
    atomicAdd(ideg + k * NN + dst, 1);
}

// ---- prefix-sum A: per-block exclusive scan + block sums ----
__global__ __launch_bounds__(256) void k_scanA(const int* __restrict__ ideg,
                                               int* __restrict__ off,
                                               int* __restrict__ bsum) {
    __shared__ int s[256];
    int tid = threadIdx.x;
    int i = blockIdx.x * 256 + tid;
    int v = (i < 4 * NN) ? ideg[i] : 0;
    s[tid] = v;
    __syncthreads();
    for (int d = 1; d < 256; d <<= 1) {
        int t = (tid >= d) ? s[tid - d] : 0;
        __syncthreads();
        s[tid] += t;
        __syncthreads();
    }
    if (i < 4 * NN) off[i] = s[tid] - v;
    if (tid == 255) bsum[blockIdx.x] = s[255];
}

// ---- prefix-sum B: scan the 782 block sums in place ----
__global__ __launch_bounds__(256) void k_scanB(int* __restrict__ bsum, int nb) {
    __shared__ int s[256];
    __shared__ int carry;
    int tid = threadIdx.x;
    if (tid == 0) carry = 0;
    __syncthreads();
    for (int base = 0; base < nb; base += 256) {
        int i = base + tid;
        int v = (i < nb) ? bsum[i] : 0;
        s[tid] = v;
        __syncthreads();
        for (int d = 1; d < 256; d <<= 1) {
            int t = (tid >= d) ? s[tid - d] : 0;
            __syncthreads();
            s[tid] += t;
            __syncthreads();
        }
        int total = s[255];
        int c = carry;
        if (i < nb) bsum[i] = s[tid] - v + c;
        __syncthreads();
        if (tid == 0) carry = c + total;
        __syncthreads();
    }
}

// ---- prefix-sum C + dinv + cursor zero ----
__global__ __launch_bounds__(256) void k_scanC(int* __restrict__ off,
                                               const int* __restrict__ bsum,
                                               const int* __restrict__ ideg,
                                               float* __restrict__ dinv,
                                               int* __restrict__ cur) {
    int i = blockIdx.x * 256 + threadIdx.x;
    if (i < 4 * NN) {
        off[i] += bsum[blockIdx.x];
        dinv[i] = rsqrtf((float)(ideg[i] + 1));
        cur[i] = 0;
    }
    if (i == 0) off[4 * NN] = 4 * EE;
}

// ---- shared GEMM body: [optional BN+leaky+residual] then h_bf = (e.*rel)@W ----
// mode 0: prev=feat (stride 0), no BN.  mode 1: prev=feat, BN(agg), write e1.
// mode 2: prev=e1 (stride NN*DD), BN(agg), no write.
__device__ __forceinline__ void gemm_body(
    float* __restrict__ Wl, float (*__restrict__ xl)[68], int bxl, int tid,
    const float* __restrict__ prevbuf, size_t prev_ka_stride,
    const float* __restrict__ agg, const float* __restrict__ stats,
    const float* __restrict__ gamma, const float* __restrict__ beta,
    const float* __restrict__ rels, const float* __restrict__ W,
    float* __restrict__ e1, unsigned short* __restrict__ h_bf, int mode) {
    int ka = bxl / 3125;
    int row0 = (bxl - ka * 3125) * 16;
    {
        const f4* W4 = (const f4*)W;
        f4* Wl4 = (f4*)Wl;
        Wl4[tid] = W4[tid];
        Wl4[tid + 256] = W4[tid + 256];
        Wl4[tid + 512] = W4[tid + 512];
        Wl4[tid + 768] = W4[tid + 768];
    }
    int rl = tid >> 4, c4 = (tid & 15) * 4;
    int row = row0 + rl;
    size_t kabase = (size_t)ka * NN * DD;
    {
        f4 pv = *(const f4*)(prevbuf + (size_t)ka * prev_ka_stride + (size_t)row * DD + c4);
        if (mode > 0) {
            f4 av = *(const f4*)(agg + kabase + (size_t)row * DD + c4);
            float* a = &av.x;
            float* p = &pv.x;
            #pragma unroll
            for (int j = 0; j < 4; ++j) {
                int col = c4 + j;
                float mean = stats[ka * 128 + col] * (1.0f / NN);
                float m2 = stats[ka * 128 + 64 + col] * (1.0f / NN);
                float inv = rsqrtf(m2 - mean * mean + BN_EPS);
                float xn = gamma[col] * (a[j] - mean) * inv + beta[col];
                p[j] += (xn >= 0.f) ? xn : NEG * xn;
            }
            if (mode == 1) *(f4*)(e1 + kabase + (size_t)row * DD + c4) = pv;
        }
        f4 rv = *(const f4*)(rels + ka * 64 + c4);
        xl[rl][c4 + 0] = pv.x * rv.x;
        xl[rl][c4 + 1] = pv.y * rv.y;
        xl[rl][c4 + 2] = pv.z * rv.z;
        xl[rl][c4 + 3] = pv.w * rv.w;
    }
    __syncthreads();
    float ax = 0.f, ay = 0.f, az = 0.f, aw = 0.f;
    #pragma unroll
    for (int kk = 0; kk < 64; ++kk) {
        float xv = xl[rl][kk];
        const float* wrow = Wl + kk * 64 + c4;
        ax += xv * wrow[0];
        ay += xv * wrow[1];
        az += xv * wrow[2];
        aw += xv * wrow[3];
    }
    ushort4 o;
    o.x = f2b(ax); o.y = f2b(ay); o.z = f2b(az); o.w = f2b(aw);
    *(ushort4*)(h_bf + kabase + (size_t)row * DD + c4) = o;
}

// ---- mega-kernel: CSR fill (blocks 0..12499) || layer-0 GEMM (12500..24999) ----
__global__ __launch_bounds__(256) void k_fill_gemm0(
    const int* __restrict__ e0, const int* __restrict__ e1,
    const int* __restrict__ e2, const int* __restrict__ e3,
    const int* __restrict__ off, int* __restrict__ cur, int* __restrict__ csr,
    const float* __restrict__ feat, const float* __restrict__ rels,
    const float* __restrict__ W, unsigned short* __restrict__ h_bf) {
    __shared__ float Wl[4096];
    __shared__ float xl[16][68];
    int bx = blockIdx.x;
    int tid = threadIdx.x;
    if (bx < 12500) {
        int idx = bx * 256 + tid;
        int k = idx / EE;
        int e = idx - k * EE;
        const int* ed = (k == 0) ? e0 : (k == 1) ? e1 : (k == 2) ? e2 : e3;
        int src = ed[e], dst = ed[EE + e];
        int p = atomicAdd(cur + k * NN + dst, 1);
        csr[off[k * NN + dst] + p] = k * NN + src;    // flat src
    } else {
        gemm_body(Wl, xl, bx - 12500, tid, feat, (size_t)0,
                  nullptr, nullptr, nullptr, nullptr, rels, W,
                  nullptr, h_bf, 0);
    }
}

// ---- standalone GEMM (layers 1,2) ----
__global__ __launch_bounds__(256) void k_gemm(
    const float* __restrict__ prevbuf, size_t prev_ka_stride,
    const float* __restrict__ agg, const float* __restrict__ stats,
    const float* __restrict__ gamma, const float* __restrict__ beta,
    const float* __restrict__ rels, const float* __restrict__ W,
    float* __restrict__ e1, unsigned short* __restrict__ h_bf, int mode) {
    __shared__ float Wl[4096];
    __shared__ float xl[16][68];
    gemm_body(Wl, xl, blockIdx.y * 3125 + blockIdx.x, threadIdx.x,
              prevbuf, prev_ka_stride, agg, stats, gamma, beta,
              rels, W, e1, h_bf, mode);
}

// ---- gather: wave = 1 dst node; lane = (edge-group g, feature-quad fq) ----
__global__ __launch_bounds__(256) void k_gather(
    const unsigned short* __restrict__ h_bf, const int* __restrict__ csr,
    const int* __restrict__ off, const float* __restrict__ dinv,
    const float* __restrict__ bias, float* __restrict__ dstbuf) {
    int tid = threadIdx.x;
    int lane = tid & 63, w = tid >> 6;
    int v = blockIdx.x * 4 + w;               // flat node id (relation-major)
    int g = lane >> 4, fq = lane & 15;
    int s0 = off[v], s1 = off[v + 1];
    float di = dinv[v];
    float ax = 0.f, ay = 0.f, az = 0.f, aw = 0.f;
    #pragma unroll 2
    for (int i = s0 + g; i < s1; i += 4) {
        int sf = csr[i];
        float nm = dinv[sf] * di;
        ushort4 hv = *(const ushort4*)(h_bf + (size_t)sf * DD + fq * 4);
        ax += b2f(hv.x) * nm;
        ay += b2f(hv.y) * nm;
        az += b2f(hv.z) * nm;
        aw += b2f(hv.w) * nm;
    }
    ax += __shfl_xor(ax, 16); ay += __shfl_xor(ay, 16);
    az += __shfl_xor(az, 16); aw += __shfl_xor(aw, 16);
    ax += __shfl_xor(ax, 32); ay += __shfl_xor(ay, 32);
    az += __shfl_xor(az, 32); aw += __shfl_xor(aw, 32);
    if (lane < 16) {
        ushort4 hd = *(const ushort4*)(h_bf + (size_t)v * DD + fq * 4);
        float d2 = di * di;
        f4 bv = *(const f4*)(bias + fq * 4);
        f4 o;
        o.x = bv.x + b2f(hd.x) * d2 + ax;
        o.y = bv.y + b2f(hd.y) * d2 + ay;
        o.z = bv.z + b2f(hd.z) * d2 + az;
        o.w = bv.w + b2f(hd.w) * d2 + aw;
        *(f4*)(dstbuf + (size_t)v * DD + fq * 4) = o;
    }
}

// ---- BN column stats (sum, sumsq): per-wave partials + moderate atomics ----
__global__ __launch_bounds__(256) void k_bnstats(
    const float* __restrict__ agg, float* __restrict__ stats) {
    int ka = blockIdx.y;
    int col = threadIdx.x & 63;
    int w = threadIdx.x >> 6;
    long r0 = (long)blockIdx.x * 256 + w * 64;
    float s = 0.f, s2 = 0.f;
    size_t base = (size_t)ka * NN * DD;
    for (int i = 0; i < 64; ++i) {
        long r = r0 + i;
        if (r < NN) {
            float v = agg[base + r * DD + col];
            s += v;
            s2 += v * v;
        }
    }
    atomicAdd(stats + ka * 128 + col, s);
    atomicAdd(stats + ka * 128 + 64 + col, s2);
}

extern "C" void kernel_launch(void* const* d_in, const int* in_sizes, int n_in,
                              void* d_out, int out_size, void* d_ws, size_t ws_size,
                              hipStream_t stream) {
    const float* feat = (const float*)d_in[0];
    const float* poir = (const float*)d_in[1];
    const float* sr   = (const float*)d_in[2];
    const float* dr   = (const float*)d_in[3];
    const float* nr   = (const float*)d_in[4];
    const int* e_poi  = (const int*)d_in[5];
    const int* e_s    = (const int*)d_in[6];
    const int* e_d    = (const int*)d_in[7];
    const int* e_n    = (const int*)d_in[8];
    const float* gcnW = (const float*)d_in[9];
    const float* gcnb = (const float*)d_in[10];
    const float* bng  = (const float*)d_in[11];
    const float* bnb  = (const float*)d_in[12];
    const float* relW = (const float*)d_in[13];
    const float* relb = (const float*)d_in[14];

    float* out = (float*)d_out;
    float* rel_out = out + (size_t)4 * NN * DD;
    float* ws = (float*)d_ws;

    // workspace layout (4-byte words, 16B-aligned regions)
    size_t o = 0;
    auto alloc = [&](size_t words) { o = (o + 3) & ~(size_t)3; size_t r = o; o += words; return r; };
    float* dinv     = ws + alloc(200000);
    float* rels_all = ws + alloc(1024);
    float* stats    = ws + alloc(1024);                   // [2 layers][512]
    int*   ideg     = (int*)(ws + alloc(200000));
    int*   off      = (int*)(ws + alloc(200001));
    int*   bsum     = (int*)(ws + alloc(800));
    int*   curp     = (int*)(ws + alloc(200000));
    int*   csr      = (int*)(ws + alloc((size_t)4 * EE));
    unsigned short* h_bf = (unsigned short*)(ws + alloc((size_t)2 * NN * DD));
    float* agg      = ws + alloc((size_t)4 * NN * DD);
    float* e1       = ws + alloc((size_t)4 * NN * DD);

    const int* E0 = e_n;  const int* E1 = e_poi;
    const int* E2 = e_s;  const int* E3 = e_d;
    const int NB = (4 * NN + 255) / 256;   // 782

    hipMemsetAsync(ideg, 0, 4 * NN * sizeof(int), stream);
    k_rels<<<1, 256, 0, stream>>>(nr, poir, sr, dr, relW, relb, rels_all, rel_out, stats);
    k_deg_count<<<(4 * EE) / 256, 256, 0, stream>>>(E0, E1, E2, E3, ideg);
    k_scanA<<<NB, 256, 0, stream>>>(ideg, off, bsum);
    k_scanB<<<1, 256, 0, stream>>>(bsum, NB);
    k_scanC<<<NB, 256, 0, stream>>>(off, bsum, ideg, dinv, curp);

    // layer 0: CSR fill || GEMM0 fused
    k_fill_gemm0<<<25000, 256, 0, stream>>>(E0, E1, E2, E3, off, curp, csr,
                                            feat, rels_all + 0, gcnW + 0, h_bf);
    k_gather<<<50000, 256, 0, stream>>>(h_bf, csr, off, dinv, gcnb + 0, agg);
    k_bnstats<<<dim3(196, 4), 256, 0, stream>>>(agg, stats + 0);

    // layer 1
    k_gemm<<<dim3(3125, 4), 256, 0, stream>>>(
        feat, (size_t)0, agg, stats + 0, bng + 0, bnb + 0,
        rels_all + 256, gcnW + 4096, e1, h_bf, 1);
    k_gather<<<50000, 256, 0, stream>>>(h_bf, csr, off, dinv, gcnb + 64, agg);
    k_bnstats<<<dim3(196, 4), 256, 0, stream>>>(agg, stats + 512);

    // layer 2
    k_gemm<<<dim3(3125, 4), 256, 0, stream>>>(
        e1, (size_t)(NN * DD), agg, stats + 512, bng + 64, bnb + 64,
        rels_all + 512, gcnW + 8192, nullptr, h_bf, 2);
    k_gather<<<50000, 256, 0, stream>>>(h_bf, csr, off, dinv, gcnb + 128, out);
}

// Round 7
// 872.086 us; speedup vs baseline: 2.2177x; 1.0366x over previous
//
#include <hip/hip_runtime.h>

#define NN 50000
#define DD 64
#define EE 800000
#define BN_EPS 1e-5f
#define NEG 0.01f

typedef float4 f4;

__device__ __forceinline__ float b2f(unsigned short u) {
    return __uint_as_float(((unsigned)u) << 16);
}
__device__ __forceinline__ unsigned short f2b(float x) {
    unsigned u = __float_as_uint(x);
    u += 0x7fffu + ((u >> 16) & 1u);   // RNE
    return (unsigned short)(u >> 16);
}

// ---- mega: deg-count (blocks 0..12499, 4-replica histogram) + rels (block 12500) ----
__global__ __launch_bounds__(256) void k_deg_rels(
    const int* __restrict__ e0, const int* __restrict__ e1,
    const int* __restrict__ e2, const int* __restrict__ e3,
    int* __restrict__ ideg4,
    const float* __restrict__ nr, const float* __restrict__ poir,
    const float* __restrict__ sr, const float* __restrict__ dr,
    const float* __restrict__ relW, const float* __restrict__ relb,
    float* __restrict__ rels_all, float* __restrict__ rel_out,
    float* __restrict__ stats) {
    int tid = threadIdx.x;
    if (blockIdx.x < 12500) {
        int idx = blockIdx.x * 256 + tid;
        int k = idx / EE;
        int e = idx - k * EE;
        const int* ed = (k == 0) ? e0 : (k == 1) ? e1 : (k == 2) ? e2 : e3;
        int dst = ed[EE + e];
        atomicAdd(ideg4 + (size_t)(blockIdx.x & 3) * 200000 + k * NN + dst, 1);
    } else {
        __shared__ float cur[4][64];
        stats[tid] = 0.f; stats[tid + 256] = 0.f;
        stats[tid + 512] = 0.f; stats[tid + 768] = 0.f;
        int k = tid >> 6, j = tid & 63;
        const float* r0 = (k == 0) ? nr : (k == 1) ? poir : (k == 2) ? sr : dr;
        float v = r0[j];
        cur[k][j] = v;
        rels_all[(0 * 4 + k) * 64 + j] = v;
        __syncthreads();
        for (int s = 0; s < 3; ++s) {
            const float* W = relW + s * 4096;
            float acc = relb[s * 64 + j];
            #pragma unroll 8
            for (int kk = 0; kk < 64; ++kk) acc += cur[k][kk] * W[j * 64 + kk];
            __syncthreads();
            cur[k][j] = acc;
            rels_all[((s + 1) * 4 + k) * 64 + j] = acc;
            __syncthreads();
        }
        rel_out[k * 64 + j] = cur[k][j];
    }
}

// ---- prefix-sum A: sum 4 replicas, per-block exclusive scan + block sums ----
__global__ __launch_bounds__(256) void k_scanA(int* __restrict__ ideg4,
                                               int* __restrict__ off,
                                               int* __restrict__ bsum) {
    __shared__ int s[256];
    int tid = threadIdx.x;
    int i = blockIdx.x * 256 + tid;
    int v = 0;
    if (i < 4 * NN) {
        v = ideg4[i] + ideg4[i + 200000] + ideg4[i + 400000] + ideg4[i + 600000];
        ideg4[i] = v;      // total degree for dinv
    }
    s[tid] = v;
    __syncthreads();
    for (int d = 1; d < 256; d <<= 1) {
        int t = (tid >= d) ? s[tid - d] : 0;
        __syncthreads();
        s[tid] += t;
        __syncthreads();
    }
    if (i < 4 * NN) off[i] = s[tid] - v;
    if (tid == 255) bsum[blockIdx.x] = s[255];
}

// ---- prefix-sum B: scan the 782 block sums in place ----
__global__ __launch_bounds__(256) void k_scanB(int* __restrict__ bsum, int nb) {
    __shared__ int s[256];
    __shared__ int carry;
    int tid = threadIdx.x;
    if (tid == 0) carry = 0;
    __syncthreads();
    for (int base = 0; base < nb; base += 256) {
        int i = base + tid;
        int v = (i < nb) ? bsum[i] : 0;
        s[tid] = v;
        __syncthreads();
        for (int d = 1; d < 256; d <<= 1) {
            int t = (tid >= d) ? s[tid - d] : 0;
            __syncthreads();
            s[tid] += t;
            __syncthreads();
        }
        int total = s[255];
        int c = carry;
        if (i < nb) bsum[i] = s[tid] - v + c;
        __syncthreads();
        if (tid == 0) carry = c + total;
        __syncthreads();
    }
}

// ---- prefix-sum C + dinv + cursor zero ----
__global__ __launch_bounds__(256) void k_scanC(int* __restrict__ off,
                                               const int* __restrict__ bsum,
                                               const int* __restrict__ ideg,
                                               float* __restrict__ dinv,
                                               int* __restrict__ cur) {
    int i = blockIdx.x * 256 + threadIdx.x;
    if (i < 4 * NN) {
        off[i] += bsum[blockIdx.x];
        dinv[i] = rsqrtf((float)(ideg[i] + 1));
        cur[i] = 0;
    }
    if (i == 0) off[4 * NN] = 4 * EE;
}

// ---- shared GEMM body: [optional BN+leaky+residual] then h_bf = (e.*rel)@W ----
__device__ __forceinline__ void gemm_body(
    float* __restrict__ Wl, float (*__restrict__ xl)[68], int bxl, int tid,
    const float* __restrict__ prevbuf, size_t prev_ka_stride,
    const float* __restrict__ agg, const float* __restrict__ stats,
    const float* __restrict__ gamma, const float* __restrict__ beta,
    const float* __restrict__ rels, const float* __restrict__ W,
    float* __restrict__ e1, unsigned short* __restrict__ h_bf, int mode) {
    int ka = bxl / 3125;
    int row0 = (bxl - ka * 3125) * 16;
    {
        const f4* W4 = (const f4*)W;
        f4* Wl4 = (f4*)Wl;
        Wl4[tid] = W4[tid];
        Wl4[tid + 256] = W4[tid + 256];
        Wl4[tid + 512] = W4[tid + 512];
        Wl4[tid + 768] = W4[tid + 768];
    }
    int rl = tid >> 4, c4 = (tid & 15) * 4;
    int row = row0 + rl;
    size_t kabase = (size_t)ka * NN * DD;
    {
        f4 pv = *(const f4*)(prevbuf + (size_t)ka * prev_ka_stride + (size_t)row * DD + c4);
        if (mode > 0) {
            f4 av = *(const f4*)(agg + kabase + (size_t)row * DD + c4);
            float* a = &av.x;
            float* p = &pv.x;
            #pragma unroll
            for (int j = 0; j < 4; ++j) {
                int col = c4 + j;
                float mean = stats[ka * 128 + col] * (1.0f / NN);
                float m2 = stats[ka * 128 + 64 + col] * (1.0f / NN);
                float inv = rsqrtf(m2 - mean * mean + BN_EPS);
                float xn = gamma[col] * (a[j] - mean) * inv + beta[col];
                p[j] += (xn >= 0.f) ? xn : NEG * xn;
            }
            if (mode == 1) *(f4*)(e1 + kabase + (size_t)row * DD + c4) = pv;
        }
        f4 rv = *(const f4*)(rels + ka * 64 + c4);
        xl[rl][c4 + 0] = pv.x * rv.x;
        xl[rl][c4 + 1] = pv.y * rv.y;
        xl[rl][c4 + 2] = pv.z * rv.z;
        xl[rl][c4 + 3] = pv.w * rv.w;
    }
    __syncthreads();
    float ax = 0.f, ay = 0.f, az = 0.f, aw = 0.f;
    #pragma unroll
    for (int kk = 0; kk < 64; ++kk) {
        float xv = xl[rl][kk];
        const float* wrow = Wl + kk * 64 + c4;
        ax += xv * wrow[0];
        ay += xv * wrow[1];
        az += xv * wrow[2];
        aw += xv * wrow[3];
    }
    ushort4 o;
    o.x = f2b(ax); o.y = f2b(ay); o.z = f2b(az); o.w = f2b(aw);
    *(ushort4*)(h_bf + kabase + (size_t)row * DD + c4) = o;
}

// ---- mega-kernel: CSR fill (blocks 0..12499) || layer-0 GEMM (12500..24999) ----
__global__ __launch_bounds__(256) void k_fill_gemm0(
    const int* __restrict__ e0, const int* __restrict__ e1,
    const int* __restrict__ e2, const int* __restrict__ e3,
    const int* __restrict__ off, int* __restrict__ cur, int* __restrict__ csr,
    const float* __restrict__ feat, const float* __restrict__ rels,
    const float* __restrict__ W, unsigned short* __restrict__ h_bf) {
    __shared__ float Wl[4096];
    __shared__ float xl[16][68];
    int bx = blockIdx.x;
    int tid = threadIdx.x;
    if (bx < 12500) {
        int idx = bx * 256 + tid;
        int k = idx / EE;
        int e = idx - k * EE;
        const int* ed = (k == 0) ? e0 : (k == 1) ? e1 : (k == 2) ? e2 : e3;
        int src = ed[e], dst = ed[EE + e];
        int p = atomicAdd(cur + k * NN + dst, 1);
        csr[off[k * NN + dst] + p] = k * NN + src;    // flat src
    } else {
        gemm_body(Wl, xl, bx - 12500, tid, feat, (size_t)0,
                  nullptr, nullptr, nullptr, nullptr, rels, W,
                  nullptr, h_bf, 0);
    }
}

// ---- standalone GEMM (layers 1,2) ----
__global__ __launch_bounds__(256) void k_gemm(
    const float* __restrict__ prevbuf, size_t prev_ka_stride,
    const float* __restrict__ agg, const float* __restrict__ stats,
    const float* __restrict__ gamma, const float* __restrict__ beta,
    const float* __restrict__ rels, const float* __restrict__ W,
    float* __restrict__ e1, unsigned short* __restrict__ h_bf, int mode) {
    __shared__ float Wl[4096];
    __shared__ float xl[16][68];
    gemm_body(Wl, xl, blockIdx.y * 3125 + blockIdx.x, threadIdx.x,
              prevbuf, prev_ka_stride, agg, stats, gamma, beta,
              rels, W, e1, h_bf, mode);
}

// ---- gather: wave = 1 dst node; lane = (edge-group g of 8, col-chunk c8 of 8) ----
// 16-B uint4 loads (8 bf16), 8 edges in flight per wave
__global__ __launch_bounds__(256) void k_gather(
    const unsigned short* __restrict__ h_bf, const int* __restrict__ csr,
    const int* __restrict__ off, const float* __restrict__ dinv,
    const float* __restrict__ bias, float* __restrict__ dstbuf) {
    int tid = threadIdx.x;
    int lane = tid & 63, w = tid >> 6;
    int v = blockIdx.x * 4 + w;               // flat node id (relation-major)
    int g = lane >> 3, c8 = lane & 7;
    int s0 = off[v], s1 = off[v + 1];
    float di = dinv[v];
    float a0 = 0.f, a1 = 0.f, a2 = 0.f, a3 = 0.f;
    float a4 = 0.f, a5 = 0.f, a6 = 0.f, a7 = 0.f;
    const unsigned short* hcol = h_bf + c8 * 8;
    #pragma unroll 2
    for (int i = s0 + g; i < s1; i += 8) {
        int sf = csr[i];
        float nm = dinv[sf] * di;
        uint4 hv = *(const uint4*)(hcol + (size_t)sf * DD);
        a0 += __uint_as_float(hv.x << 16) * nm;
        a1 += __uint_as_float(hv.x & 0xffff0000u) * nm;
        a2 += __uint_as_float(hv.y << 16) * nm;
        a3 += __uint_as_float(hv.y & 0xffff0000u) * nm;
        a4 += __uint_as_float(hv.z << 16) * nm;
        a5 += __uint_as_float(hv.z & 0xffff0000u) * nm;
        a6 += __uint_as_float(hv.w << 16) * nm;
        a7 += __uint_as_float(hv.w & 0xffff0000u) * nm;
    }
    #pragma unroll
    for (int m = 8; m <= 32; m <<= 1) {
        a0 += __shfl_xor(a0, m); a1 += __shfl_xor(a1, m);
        a2 += __shfl_xor(a2, m); a3 += __shfl_xor(a3, m);
        a4 += __shfl_xor(a4, m); a5 += __shfl_xor(a5, m);
        a6 += __shfl_xor(a6, m); a7 += __shfl_xor(a7, m);
    }
    if (lane < 8) {
        float d2 = di * di;
        uint4 hd = *(const uint4*)(h_bf + (size_t)v * DD + lane * 8);
        f4 b0 = *(const f4*)(bias + lane * 8);
        f4 b1 = *(const f4*)(bias + lane * 8 + 4);
        f4 o0, o1;
        o0.x = b0.x + __uint_as_float(hd.x << 16) * d2 + a0;
        o0.y = b0.y + __uint_as_float(hd.x & 0xffff0000u) * d2 + a1;
        o0.z = b0.z + __uint_as_float(hd.y << 16) * d2 + a2;
        o0.w = b0.w + __uint_as_float(hd.y & 0xffff0000u) * d2 + a3;
        o1.x = b1.x + __uint_as_float(hd.z << 16) * d2 + a4;
        o1.y = b1.y + __uint_as_float(hd.z & 0xffff0000u) * d2 + a5;
        o1.z = b1.z + __uint_as_float(hd.w << 16) * d2 + a6;
        o1.w = b1.w + __uint_as_float(hd.w & 0xffff0000u) * d2 + a7;
        *(f4*)(dstbuf + (size_t)v * DD + lane * 8) = o0;
        *(f4*)(dstbuf + (size_t)v * DD + lane * 8 + 4) = o1;
    }
}

// ---- BN column stats (sum, sumsq): per-wave partials + moderate atomics ----
__global__ __launch_bounds__(256) void k_bnstats(
    const float* __restrict__ agg, float* __restrict__ stats) {
    int ka = blockIdx.y;
    int col = threadIdx.x & 63;
    int w = threadIdx.x >> 6;
    long r0 = (long)blockIdx.x * 256 + w * 64;
    float s = 0.f, s2 = 0.f;
    size_t base = (size_t)ka * NN * DD;
    for (int i = 0; i < 64; ++i) {
        long r = r0 + i;
        if (r < NN) {
            float v = agg[base + r * DD + col];
            s += v;
            s2 += v * v;
        }
    }
    atomicAdd(stats + ka * 128 + col, s);
    atomicAdd(stats + ka * 128 + 64 + col, s2);
}

extern "C" void kernel_launch(void* const* d_in, const int* in_sizes, int n_in,
                              void* d_out, int out_size, void* d_ws, size_t ws_size,
                              hipStream_t stream) {
    const float* feat = (const float*)d_in[0];
    const float* poir = (const float*)d_in[1];
    const float* sr   = (const float*)d_in[2];
    const float* dr   = (const float*)d_in[3];
    const float* nr   = (const float*)d_in[4];
    const int* e_poi  = (const int*)d_in[5];
    const int* e_s    = (const int*)d_in[6];
    const int* e_d    = (const int*)d_in[7];
    const int* e_n    = (const int*)d_in[8];
    const float* gcnW = (const float*)d_in[9];
    const float* gcnb = (const float*)d_in[10];
    const float* bng  = (const float*)d_in[11];
    const float* bnb  = (const float*)d_in[12];
    const float* relW = (const float*)d_in[13];
    const float* relb = (const float*)d_in[14];

    float* out = (float*)d_out;
    float* rel_out = out + (size_t)4 * NN * DD;
    float* ws = (float*)d_ws;

    // workspace layout (4-byte words, 16B-aligned regions)
    size_t o = 0;
    auto alloc = [&](size_t words) { o = (o + 3) & ~(size_t)3; size_t r = o; o += words; return r; };
    float* dinv     = ws + alloc(200000);
    float* rels_all = ws + alloc(1024);
    float* stats    = ws + alloc(1024);                   // [2 layers][512]
    int*   ideg4    = (int*)(ws + alloc(800000));         // 4 replicas
    int*   off      = (int*)(ws + alloc(200001));
    int*   bsum     = (int*)(ws + alloc(800));
    int*   curp     = (int*)(ws + alloc(200000));
    int*   csr      = (int*)(ws + alloc((size_t)4 * EE));
    unsigned short* h_bf = (unsigned short*)(ws + alloc((size_t)2 * NN * DD));
    float* agg      = ws + alloc((size_t)4 * NN * DD);
    float* e1       = ws + alloc((size_t)4 * NN * DD);

    const int* E0 = e_n;  const int* E1 = e_poi;
    const int* E2 = e_s;  const int* E3 = e_d;
    const int NB = (4 * NN + 255) / 256;   // 782

    hipMemsetAsync(ideg4, 0, 800000 * sizeof(int), stream);
    k_deg_rels<<<12501, 256, 0, stream>>>(E0, E1, E2, E3, ideg4,
                                          nr, poir, sr, dr, relW, relb,
                                          rels_all, rel_out, stats);
    k_scanA<<<NB, 256, 0, stream>>>(ideg4, off, bsum);
    k_scanB<<<1, 256, 0, stream>>>(bsum, NB);
    k_scanC<<<NB, 256, 0, stream>>>(off, bsum, ideg4, dinv, curp);

    // layer 0: CSR fill || GEMM0 fused
    k_fill_gemm0<<<25000, 256, 0, stream>>>(E0, E1, E2, E3, off, curp, csr,
                                            feat, rels_all + 0, gcnW + 0, h_bf);
    k_gather<<<50000, 256, 0, stream>>>(h_bf, csr, off, dinv, gcnb + 0, agg);
    k_bnstats<<<dim3(196, 4), 256, 0, stream>>>(agg, stats + 0);

    // layer 1
    k_gemm<<<dim3(3125, 4), 256, 0, stream>>>(
        feat, (size_t)0, agg, stats + 0, bng + 0, bnb + 0,
        rels_all + 256, gcnW + 4096, e1, h_bf, 1);
    k_gather<<<50000, 256, 0, stream>>>(h_bf, csr, off, dinv, gcnb + 64, agg);
    k_bnstats<<<dim3(196, 4), 256, 0, stream>>>(agg, stats + 512);

    // layer 2
    k_gemm<<<dim3(3125, 4), 256, 0, stream>>>(
        e1, (size_t)(NN * DD), agg, stats + 512, bng + 64, bnb + 64,
        rels_all + 512, gcnW + 8192, nullptr, h_bf, 2);
    k_gather<<<50000, 256, 0, stream>>>(h_bf, csr, off, dinv, gcnb + 128, out);
}